// Round 1
// 526.668 us; speedup vs baseline: 1.0338x; 1.0338x over previous
//
#include <hip/hip_runtime.h>
#include <hip/hip_bf16.h>
#include <stdint.h>

// Problem constants
#define NEXP   16
#define TTOK   32768
#define HIN    2048
#define RNK    128
#define OOUT   2048
#define TE     (TTOK / NEXP)   // 2048 tokens per expert
#define LORA_SCALE 0.25f       // alpha/rank = 32/128

typedef __bf16 bf16_t;
typedef bf16_t bf16x8 __attribute__((ext_vector_type(8)));
typedef bf16_t bf16x4 __attribute__((ext_vector_type(4)));
typedef float  f32x4  __attribute__((ext_vector_type(4)));

// ---------------------------------------------------------------------------
// Per-expert transpose + fp32->bf16 convert: src f32 [E][Rr][Cc] -> dst bf16 [E][Cc][Rr]
// (unchanged from verified baseline)
// ---------------------------------------------------------------------------
__global__ void transpose_cvt_kernel(const float* __restrict__ src,
                                     bf16_t* __restrict__ dst,
                                     int Rr, int Cc)
{
    __shared__ float tile[32][33];
    const int e  = blockIdx.z;
    const int c0 = blockIdx.x * 32;
    const int r0 = blockIdx.y * 32;
    const float* s = src + (size_t)e * Rr * Cc;
    bf16_t*      d = dst + (size_t)e * Rr * Cc;
    const int tx = threadIdx.x & 31;
    const int ty = threadIdx.x >> 5;   // 0..7
#pragma unroll
    for (int j = 0; j < 32; j += 8)
        tile[ty + j][tx] = s[(size_t)(r0 + ty + j) * Cc + (c0 + tx)];
    __syncthreads();
#pragma unroll
    for (int j = 0; j < 32; j += 8)
        d[(size_t)(c0 + ty + j) * Rr + (r0 + tx)] = (bf16_t)tile[tx][ty + j];
}

// ---------------------------------------------------------------------------
// Fused grouped LoRA: per 128-token block,
//   phase 1: L[128][128] = x_tile[128][2048] @ At[e]^T   (acc fp32, L -> bf16 LDS)
//   phase 2: out_tile[128][2048] = L @ Btw[e]^T * scale
// At  bf16 [E][RNK][HIN]   (k-contiguous fragments for GEMM-1 B operand)
// Btw bf16 [E][OOUT][RNK]  (k-contiguous fragments for GEMM-2 B operand)
//
// 512 threads = 8 waves (wave grid 4m x 2n), wave tile 32x64.
// Swapped-operand MFMA (mfma(B,A)): lane&15 = output ROW, q*4+reg = output COL
// -> L written as ds_write_b64, epilogue as global_store_dwordx4.
// All LDS tiles XOR-swizzled: byte ^= ((row&7)<<4)  (reg-staged both sides).
// LDS: [0,64K) = phase-1 staging dbuf (Xs 2x16K @0, As 2x16K @32K),
//      reused in phase 2 as B dbuf (2x32K); [64K,96K) = L tile.
// ---------------------------------------------------------------------------
__global__ __launch_bounds__(512, 2)
void fused_lora(const float* __restrict__ X,
                const bf16_t* __restrict__ Atw,
                const bf16_t* __restrict__ Btw,
                float* __restrict__ Out)
{
    __shared__ __align__(16) char lds[98304];

    const int tid  = threadIdx.x;
    const int blk  = blockIdx.x;
    const int m0   = blk * 128;
    const int e    = blk >> 4;            // 16 blocks per expert

    const int wave = tid >> 6;            // 0..7
    const int lane = tid & 63;
    const int lm   = lane & 15;
    const int q    = lane >> 4;
    const int wr   = (wave >> 1) * 32;    // m offset: 0/32/64/96
    const int wc   = (wave & 1) * 64;     // r (phase1) / n (phase2) offset: 0/64

    // staging map: 4 threads per row, 128 rows
    const int sr  = tid >> 2;             // 0..127
    const int sc  = tid & 3;              // 0..3
    const int ssw = (sr & 7) << 4;        // staging-row swizzle

    const float*  xg = X   + (size_t)(m0 + sr) * HIN + sc * 16;
    const bf16_t* ag = Atw + ((size_t)e * RNK + sr) * HIN + sc * 16;

    f32x4  xa[4];
    bf16x8 ar[2];
    f32x4  acc1[2][4] = {};

    // ---------------- phase 1: L = x @ A^T, K = 2048, BK = 64 ----------------
    // prologue: load + stage iter 0 into buf 0
    {
#pragma unroll
        for (int i = 0; i < 4; ++i) xa[i] = *(const f32x4*)(xg + i * 4);
        ar[0] = *(const bf16x8*)(ag);
        ar[1] = *(const bf16x8*)(ag + 8);
        bf16x8 c0, c1;
#pragma unroll
        for (int i = 0; i < 4; ++i) {
            c0[i] = (bf16_t)xa[0][i]; c0[4 + i] = (bf16_t)xa[1][i];
            c1[i] = (bf16_t)xa[2][i]; c1[4 + i] = (bf16_t)xa[3][i];
        }
        char* bx = lds + sr * 128;
        *(bf16x8*)(bx + ((sc * 32     ) ^ ssw)) = c0;
        *(bf16x8*)(bx + ((sc * 32 + 16) ^ ssw)) = c1;
        char* ba = lds + 32768 + sr * 128;
        *(bf16x8*)(ba + ((sc * 32     ) ^ ssw)) = ar[0];
        *(bf16x8*)(ba + ((sc * 32 + 16) ^ ssw)) = ar[1];
    }
    __syncthreads();

    for (int it = 0; it < 32; ++it) {
        const int cur = it & 1;
        // prefetch next K-slab (global -> regs); latency drains under MFMA
        if (it < 31) {
            const float*  px = xg + (it + 1) * 64;
            const bf16_t* pa = ag + (it + 1) * 64;
#pragma unroll
            for (int i = 0; i < 4; ++i) xa[i] = *(const f32x4*)(px + i * 4);
            ar[0] = *(const bf16x8*)(pa);
            ar[1] = *(const bf16x8*)(pa + 8);
        }
        // compute on buf cur
        const char* xb = lds + cur * 16384;
        const char* ab = lds + 32768 + cur * 16384;
#pragma unroll
        for (int ks = 0; ks < 2; ++ks) {
            bf16x8 XF[2], AF[4];
#pragma unroll
            for (int mt = 0; mt < 2; ++mt) {
                const int row = wr + mt * 16 + lm;
                XF[mt] = *(const bf16x8*)(xb + row * 128 +
                           ((ks * 64 + q * 16) ^ ((row & 7) << 4)));
            }
#pragma unroll
            for (int rt = 0; rt < 4; ++rt) {
                const int row = wc + rt * 16 + lm;
                AF[rt] = *(const bf16x8*)(ab + row * 128 +
                           ((ks * 64 + q * 16) ^ ((row & 7) << 4)));
            }
#pragma unroll
            for (int mt = 0; mt < 2; ++mt)
#pragma unroll
                for (int rt = 0; rt < 4; ++rt)
                    acc1[mt][rt] = __builtin_amdgcn_mfma_f32_16x16x32_bf16(
                        AF[rt], XF[mt], acc1[mt][rt], 0, 0, 0);
        }
        // stage next slab into buf cur^1 (waits on its global loads)
        if (it < 31) {
            bf16x8 c0, c1;
#pragma unroll
            for (int i = 0; i < 4; ++i) {
                c0[i] = (bf16_t)xa[0][i]; c0[4 + i] = (bf16_t)xa[1][i];
                c1[i] = (bf16_t)xa[2][i]; c1[4 + i] = (bf16_t)xa[3][i];
            }
            char* bx = lds + (cur ^ 1) * 16384 + sr * 128;
            *(bf16x8*)(bx + ((sc * 32     ) ^ ssw)) = c0;
            *(bf16x8*)(bx + ((sc * 32 + 16) ^ ssw)) = c1;
            char* ba = lds + 32768 + (cur ^ 1) * 16384 + sr * 128;
            *(bf16x8*)(ba + ((sc * 32     ) ^ ssw)) = ar[0];
            *(bf16x8*)(ba + ((sc * 32 + 16) ^ ssw)) = ar[1];
        }
        __syncthreads();
    }

    // ---------------- transition: L -> LDS (bf16), load phase-2 A frags -----
    // issue B chunk-0 loads early so they drain under the L-write + barrier
    bf16x8 br[4];
    const bf16_t* bg0 = Btw + ((size_t)e * OOUT + sr) * RNK + sc * 32;
#pragma unroll
    for (int i = 0; i < 4; ++i) br[i] = *(const bf16x8*)(bg0 + i * 8);

    // swapped-operand layout: lane holds L[m = wr+mt*16+lm][r = wc+rt*16+q*4+reg]
    char* Lbase = lds + 65536;
#pragma unroll
    for (int mt = 0; mt < 2; ++mt) {
        const int m   = wr + mt * 16 + lm;
        const int msw = (m & 7) << 4;
#pragma unroll
        for (int rt = 0; rt < 4; ++rt) {
            const int r0 = wc + rt * 16 + q * 4;
            bf16x4 v;
#pragma unroll
            for (int i = 0; i < 4; ++i) v[i] = (bf16_t)acc1[mt][rt][i];
            *(bf16x4*)(Lbase + m * 256 + ((r0 * 2) ^ msw)) = v;
        }
    }
    __syncthreads();   // L visible to all waves; phase-1 staging bufs now dead

    // A-operand fragments for phase 2: load ONCE, reuse for all 16 N-chunks
    bf16x8 af2[2][4];
#pragma unroll
    for (int mt = 0; mt < 2; ++mt) {
        const int m   = wr + mt * 16 + lm;
        const int msw = (m & 7) << 4;
#pragma unroll
        for (int ks = 0; ks < 4; ++ks)
            af2[mt][ks] = *(const bf16x8*)(Lbase + m * 256 +
                             ((ks * 64 + q * 16) ^ msw));
    }

    // stage B chunk 0 into buf 0 (reuses phase-1 staging region)
    {
        char* bb = lds + sr * 256;
#pragma unroll
        for (int i = 0; i < 4; ++i)
            *(bf16x8*)(bb + ((sc * 64 + i * 16) ^ ssw)) = br[i];
    }
    __syncthreads();

    // ---------------- phase 2: out = L @ B^T * scale, 16 chunks of 128 cols --
    for (int c = 0; c < 16; ++c) {
        const int cur = c & 1;
        if (c < 15) {
            const bf16_t* bg = bg0 + (size_t)(c + 1) * 128 * RNK;
#pragma unroll
            for (int i = 0; i < 4; ++i) br[i] = *(const bf16x8*)(bg + i * 8);
        }
        f32x4 acc2[2][4] = {};
        const char* bb = lds + cur * 32768;
#pragma unroll
        for (int nt = 0; nt < 4; ++nt) {
            const int n   = wc + nt * 16 + lm;
            const int nsw = (n & 7) << 4;
#pragma unroll
            for (int ks = 0; ks < 4; ++ks) {
                const bf16x8 bfr = *(const bf16x8*)(bb + n * 256 +
                                      ((ks * 64 + q * 16) ^ nsw));
                acc2[0][nt] = __builtin_amdgcn_mfma_f32_16x16x32_bf16(
                    bfr, af2[0][ks], acc2[0][nt], 0, 0, 0);
                acc2[1][nt] = __builtin_amdgcn_mfma_f32_16x16x32_bf16(
                    bfr, af2[1][ks], acc2[1][nt], 0, 0, 0);
            }
        }
        // epilogue: lane holds out[m][n0..n0+4) -> coalesced f32x4 stores
#pragma unroll
        for (int mt = 0; mt < 2; ++mt) {
            const int gm = m0 + wr + mt * 16 + lm;
            float* orow = Out + (size_t)gm * OOUT + c * 128 + wc + q * 4;
#pragma unroll
            for (int nt = 0; nt < 4; ++nt) {
                const f32x4 v = acc2[mt][nt] * LORA_SCALE;
                *(f32x4*)(orow + nt * 16) = v;
            }
        }
        // stage next chunk into the other buffer
        if (c < 15) {
            char* bb2 = lds + (cur ^ 1) * 32768 + sr * 256;
#pragma unroll
            for (int i = 0; i < 4; ++i)
                *(bf16x8*)(bb2 + ((sc * 64 + i * 16) ^ ssw)) = br[i];
        }
        __syncthreads();
    }
}

// ---------------------------------------------------------------------------
extern "C" void kernel_launch(void* const* d_in, const int* in_sizes, int n_in,
                              void* d_out, int out_size, void* d_ws, size_t ws_size,
                              hipStream_t stream)
{
    const float* x  = (const float*)d_in[0];   // fp32 [TTOK, HIN]
    const float* la = (const float*)d_in[1];   // fp32 [E, HIN, RNK]
    const float* lb = (const float*)d_in[2];   // fp32 [E, RNK, OOUT]
    float* out = (float*)d_out;                // fp32 [TTOK, OOUT]

    // workspace layout:
    //   At  bf16 [E][RNK][HIN]   (8 MB)
    //   Btw bf16 [E][OOUT][RNK]  (8 MB)
    bf16_t* At  = (bf16_t*)d_ws;
    bf16_t* Btw = At + (size_t)NEXP * RNK * HIN;

    // transpose+convert lora_a: f32 [E][HIN][RNK] -> bf16 At [E][RNK][HIN]
    {
        dim3 g(RNK / 32, HIN / 32, NEXP);
        transpose_cvt_kernel<<<g, 256, 0, stream>>>(la, At, HIN, RNK);
    }
    // transpose+convert lora_b: f32 [E][RNK][OOUT] -> bf16 Btw [E][OOUT][RNK]
    {
        dim3 g(OOUT / 32, RNK / 32, NEXP);
        transpose_cvt_kernel<<<g, 256, 0, stream>>>(lb, Btw, RNK, OOUT);
    }
    // fused LoRA: one block per 128 tokens, 1 block/CU, 8 waves
    fused_lora<<<dim3(TTOK / 128), dim3(512), 0, stream>>>(x, At, Btw, out);
}

// Round 2
// 503.848 us; speedup vs baseline: 1.0807x; 1.0453x over previous
//
#include <hip/hip_runtime.h>
#include <hip/hip_bf16.h>
#include <stdint.h>

// Problem constants
#define NEXP   16
#define TTOK   32768
#define HIN    2048
#define RNK    128
#define OOUT   2048
#define BM     64              // tokens per block (64 -> 512 blocks -> 2 blocks/CU)
#define LORA_SCALE 0.25f       // alpha/rank = 32/128

typedef __bf16 bf16_t;
typedef bf16_t bf16x8 __attribute__((ext_vector_type(8)));
typedef bf16_t bf16x4 __attribute__((ext_vector_type(4)));
typedef float  f32x4  __attribute__((ext_vector_type(4)));

// ---------------------------------------------------------------------------
// Per-expert transpose + fp32->bf16 convert: src f32 [E][Rr][Cc] -> dst bf16 [E][Cc][Rr]
// (unchanged from verified baseline)
// ---------------------------------------------------------------------------
__global__ void transpose_cvt_kernel(const float* __restrict__ src,
                                     bf16_t* __restrict__ dst,
                                     int Rr, int Cc)
{
    __shared__ float tile[32][33];
    const int e  = blockIdx.z;
    const int c0 = blockIdx.x * 32;
    const int r0 = blockIdx.y * 32;
    const float* s = src + (size_t)e * Rr * Cc;
    bf16_t*      d = dst + (size_t)e * Rr * Cc;
    const int tx = threadIdx.x & 31;
    const int ty = threadIdx.x >> 5;   // 0..7
#pragma unroll
    for (int j = 0; j < 32; j += 8)
        tile[ty + j][tx] = s[(size_t)(r0 + ty + j) * Cc + (c0 + tx)];
    __syncthreads();
#pragma unroll
    for (int j = 0; j < 32; j += 8)
        d[(size_t)(c0 + ty + j) * Rr + (r0 + tx)] = (bf16_t)tile[tx][ty + j];
}

// ---------------------------------------------------------------------------
// Fused grouped LoRA, 64-token blocks, 2 blocks/CU (LDS = 64 KB):
//   phase 1: L[64][128] = x_tile[64][2048] @ At[e]^T   (acc fp32, L -> bf16 LDS)
//   phase 2: out_tile[64][2048] = L @ Btw[e]^T * scale
// At  bf16 [E][RNK][HIN]   (k-contiguous fragments for GEMM-1 B operand)
// Btw bf16 [E][OOUT][RNK]  (k-contiguous fragments for GEMM-2 B operand)
//
// 512 threads = 8 waves (2m x 4c), wave tile 32x32.
// Swapped-operand MFMA (mfma(B,A)): lane&15 = output ROW, q*4+reg = output COL.
// All LDS tiles XOR-swizzled: byte ^= ((row&7)<<4)  (reg-staged both sides).
// LDS map, phase 1: Xs dbuf [0,16K), As dbuf [16K,48K), L [48K,64K).
//           phase 2: B dbuf  [0,32K)+[32K,64K)  (L dead after af2 reg-load).
// ---------------------------------------------------------------------------
__global__ __launch_bounds__(512, 4)
void fused_lora(const float* __restrict__ X,
                const bf16_t* __restrict__ Atw,
                const bf16_t* __restrict__ Btw,
                float* __restrict__ Out)
{
    __shared__ __align__(16) char lds[65536];

    const int tid = threadIdx.x;
    // XCD-chunked bijective swizzle (grid=512, 512%8==0): 64 consecutive
    // blocks per XCD -> each XCD touches 2 experts' weights (L2-resident).
    const int bid = blockIdx.x;
    const int blk = (bid & 7) * 64 + (bid >> 3);
    const int m0  = blk * BM;
    const int e   = blk >> 5;             // 32 blocks per expert

    const int wave = tid >> 6;            // 0..7
    const int lane = tid & 63;
    const int lm   = lane & 15;
    const int q    = lane >> 4;
    const int wr   = (wave & 1) * 32;     // m offset: 0/32
    const int wc   = (wave >> 1) * 32;    // r (phase1) / n (phase2) offset: 0/32/64/96

    // staging maps
    const int sxr = tid >> 3, sxc = tid & 7;   // X: 64 rows x 8 slots of 8 floats
    const int sar = tid >> 2, sac = tid & 3;   // A/B: 128 rows x 4 slots

    const float*  xg = X   + (size_t)(m0 + sxr) * HIN + sxc * 8;
    const bf16_t* ag = Atw + ((size_t)e * RNK + sar) * HIN + sac * 16;

    f32x4  xa0, xa1;
    bf16x8 ar0, ar1;
    f32x4  acc1[2][2] = {};

    // ---------------- phase 1: L = x @ A^T, K = 2048, BK = 64 ----------------
    {   // prologue: stage slab 0 into buf 0
        xa0 = *(const f32x4*)(xg);
        xa1 = *(const f32x4*)(xg + 4);
        ar0 = *(const bf16x8*)(ag);
        ar1 = *(const bf16x8*)(ag + 8);
        bf16x8 cx;
#pragma unroll
        for (int i = 0; i < 4; ++i) { cx[i] = (bf16_t)xa0[i]; cx[4 + i] = (bf16_t)xa1[i]; }
        const int xsw = (sxr & 7) << 4, asw = (sar & 7) << 4;
        *(bf16x8*)(lds + sxr * 128 + ((sxc * 16) ^ xsw)) = cx;
        *(bf16x8*)(lds + 16384 + sar * 128 + ((sac * 32     ) ^ asw)) = ar0;
        *(bf16x8*)(lds + 16384 + sar * 128 + ((sac * 32 + 16) ^ asw)) = ar1;
    }
    __syncthreads();

    for (int it = 0; it < 32; ++it) {
        const int cur = it & 1;
        if (it < 31) {   // prefetch next K-slab into registers
            const float*  px = xg + (it + 1) * 64;
            const bf16_t* pa = ag + (it + 1) * 64;
            xa0 = *(const f32x4*)px;
            xa1 = *(const f32x4*)(px + 4);
            ar0 = *(const bf16x8*)pa;
            ar1 = *(const bf16x8*)(pa + 8);
        }
        const char* xb = lds + cur * 8192;
        const char* ab = lds + 16384 + cur * 16384;
#pragma unroll
        for (int ks = 0; ks < 2; ++ks) {
            bf16x8 XF[2], AF[2];
#pragma unroll
            for (int mt = 0; mt < 2; ++mt) {
                const int row = wr + mt * 16 + lm;
                XF[mt] = *(const bf16x8*)(xb + row * 128 +
                           ((ks * 64 + q * 16) ^ ((row & 7) << 4)));
            }
#pragma unroll
            for (int ct = 0; ct < 2; ++ct) {
                const int row = wc + ct * 16 + lm;
                AF[ct] = *(const bf16x8*)(ab + row * 128 +
                           ((ks * 64 + q * 16) ^ ((row & 7) << 4)));
            }
#pragma unroll
            for (int mt = 0; mt < 2; ++mt)
#pragma unroll
                for (int ct = 0; ct < 2; ++ct)
                    acc1[mt][ct] = __builtin_amdgcn_mfma_f32_16x16x32_bf16(
                        AF[ct], XF[mt], acc1[mt][ct], 0, 0, 0);
        }
        if (it < 31) {   // stage prefetched slab into the other buffer
            bf16x8 cx;
#pragma unroll
            for (int i = 0; i < 4; ++i) { cx[i] = (bf16_t)xa0[i]; cx[4 + i] = (bf16_t)xa1[i]; }
            const int xsw = (sxr & 7) << 4, asw = (sar & 7) << 4;
            *(bf16x8*)(lds + (cur ^ 1) * 8192 + sxr * 128 + ((sxc * 16) ^ xsw)) = cx;
            *(bf16x8*)(lds + 16384 + (cur ^ 1) * 16384 + sar * 128 + ((sac * 32     ) ^ asw)) = ar0;
            *(bf16x8*)(lds + 16384 + (cur ^ 1) * 16384 + sar * 128 + ((sac * 32 + 16) ^ asw)) = ar1;
        }
        __syncthreads();
    }

    // ---------------- transition: L -> LDS (bf16), load phase-2 A frags -----
    // issue B chunk-0 loads early; they drain under the L-write + barriers
    bf16x8 br[4];
    const bf16_t* bg0 = Btw + ((size_t)e * OOUT + sar) * RNK + sac * 32;
#pragma unroll
    for (int i = 0; i < 4; ++i) br[i] = *(const bf16x8*)(bg0 + i * 8);

    // swapped-operand layout: lane holds L[m = wr+mt*16+lm][r = wc+ct*16+q*4+reg]
    char* Lb = lds + 49152;
#pragma unroll
    for (int mt = 0; mt < 2; ++mt) {
        const int m   = wr + mt * 16 + lm;
        const int msw = (m & 7) << 4;
#pragma unroll
        for (int ct = 0; ct < 2; ++ct) {
            const int r0 = wc + ct * 16 + q * 4;
            bf16x4 v;
#pragma unroll
            for (int i = 0; i < 4; ++i) v[i] = (bf16_t)acc1[mt][ct][i];
            *(bf16x4*)(Lb + m * 256 + ((r0 * 2) ^ msw)) = v;
        }
    }
    __syncthreads();   // L visible to all waves

    // A-operand fragments for phase 2: load ONCE, reuse for all 16 N-chunks
    bf16x8 af2[2][4];
#pragma unroll
    for (int mt = 0; mt < 2; ++mt) {
        const int m   = wr + mt * 16 + lm;
        const int msw = (m & 7) << 4;
#pragma unroll
        for (int ks = 0; ks < 4; ++ks)
            af2[mt][ks] = *(const bf16x8*)(Lb + m * 256 + ((ks * 64 + q * 16) ^ msw));
    }

    // stage B chunk 0 into buf 0 ([0,32K): phase-1 staging region, now dead)
    {
        char* bb = lds + sar * 256;
        const int bsw = (sar & 7) << 4;
#pragma unroll
        for (int i = 0; i < 4; ++i)
            *(bf16x8*)(bb + ((sac * 64 + i * 16) ^ bsw)) = br[i];
    }
    __syncthreads();   // chunk 0 staged; all af2 reads done (buf1 may now be overwritten)

    // ---------------- phase 2: out = L @ B^T * scale, 16 chunks of 128 cols --
    for (int c = 0; c < 16; ++c) {
        const int cur = c & 1;
        if (c < 15) {
            const bf16_t* bg = bg0 + (size_t)(c + 1) * 128 * RNK;
#pragma unroll
            for (int i = 0; i < 4; ++i) br[i] = *(const bf16x8*)(bg + i * 8);
        }
        f32x4 acc2[2][2] = {};
        const char* bb = lds + cur * 32768;
#pragma unroll
        for (int nt = 0; nt < 2; ++nt) {
            const int n   = wc + nt * 16 + lm;
            const int nsw = (n & 7) << 4;
#pragma unroll
            for (int ks = 0; ks < 4; ++ks) {
                const bf16x8 BF = *(const bf16x8*)(bb + n * 256 +
                                     ((ks * 64 + q * 16) ^ nsw));
                acc2[0][nt] = __builtin_amdgcn_mfma_f32_16x16x32_bf16(
                    BF, af2[0][ks], acc2[0][nt], 0, 0, 0);
                acc2[1][nt] = __builtin_amdgcn_mfma_f32_16x16x32_bf16(
                    BF, af2[1][ks], acc2[1][nt], 0, 0, 0);
            }
        }
        // epilogue: lane holds out[m][n0..n0+4) -> f32x4 stores
#pragma unroll
        for (int mt = 0; mt < 2; ++mt) {
            const int gm = m0 + wr + mt * 16 + lm;
            float* orow = Out + (size_t)gm * OOUT + c * 128 + wc + q * 4;
#pragma unroll
            for (int nt = 0; nt < 2; ++nt) {
                const f32x4 v = acc2[mt][nt] * LORA_SCALE;
                *(f32x4*)(orow + nt * 16) = v;
            }
        }
        // stage next chunk into the other buffer
        if (c < 15) {
            char* bb2 = lds + (cur ^ 1) * 32768 + sar * 256;
            const int bsw = (sar & 7) << 4;
#pragma unroll
            for (int i = 0; i < 4; ++i)
                *(bf16x8*)(bb2 + ((sac * 64 + i * 16) ^ bsw)) = br[i];
        }
        __syncthreads();
    }
}

// ---------------------------------------------------------------------------
extern "C" void kernel_launch(void* const* d_in, const int* in_sizes, int n_in,
                              void* d_out, int out_size, void* d_ws, size_t ws_size,
                              hipStream_t stream)
{
    const float* x  = (const float*)d_in[0];   // fp32 [TTOK, HIN]
    const float* la = (const float*)d_in[1];   // fp32 [E, HIN, RNK]
    const float* lb = (const float*)d_in[2];   // fp32 [E, RNK, OOUT]
    float* out = (float*)d_out;                // fp32 [TTOK, OOUT]

    // workspace layout:
    //   At  bf16 [E][RNK][HIN]   (8 MB)
    //   Btw bf16 [E][OOUT][RNK]  (8 MB)
    bf16_t* At  = (bf16_t*)d_ws;
    bf16_t* Btw = At + (size_t)NEXP * RNK * HIN;

    // transpose+convert lora_a: f32 [E][HIN][RNK] -> bf16 At [E][RNK][HIN]
    {
        dim3 g(RNK / 32, HIN / 32, NEXP);
        transpose_cvt_kernel<<<g, 256, 0, stream>>>(la, At, HIN, RNK);
    }
    // transpose+convert lora_b: f32 [E][RNK][OOUT] -> bf16 Btw [E][OOUT][RNK]
    {
        dim3 g(OOUT / 32, RNK / 32, NEXP);
        transpose_cvt_kernel<<<g, 256, 0, stream>>>(lb, Btw, RNK, OOUT);
    }
    // fused LoRA: 64 tokens per block, 512 blocks, 2 blocks/CU, 8 waves each
    fused_lora<<<dim3(TTOK / BM), dim3(512), 0, stream>>>(x, At, Btw, out);
}